// Round 6
// baseline (111.684 us; speedup 1.0000x reference)
//
#include <hip/hip_runtime.h>

#define QLEN 1024
#define KLEN 1024
#define BSZ 2
#define NHEAD 16
#define DHEAD 64
#define RS 2048            /* BSZ*NHEAD*DHEAD floats per seq row */
#define BLK_I 64
#define BLK_J 64

#define SC2f  0.18033688011112440f   /* 0.125 * log2(e) */
#define MBIGf 1.4426950408889634e30f /* 1e30 * log2(e)  */

#define SEGP_BYTES   16777216u   /* BSZ*QLEN*KLEN*8            */
#define OPART_BYTES  16777216u   /* 2*BSZ*NHEAD*QLEN*DHEAD*4   */
#define ML_BYTES       524288u   /* 2*BSZ*NHEAD*QLEN*2*4       */

typedef __attribute__((ext_vector_type(8))) short s16x8;
typedef __attribute__((ext_vector_type(4))) float f32x4;
typedef __attribute__((ext_vector_type(2))) float f32x2;
typedef __attribute__((ext_vector_type(4))) unsigned short u16x4;

__device__ __forceinline__ unsigned short f2bf(float f) {
    union { float f; unsigned int u; } x; x.f = f;
    unsigned int r = x.u + 0x7fffu + ((x.u >> 16) & 1u);
    return (unsigned short)(r >> 16);
}
__device__ __forceinline__ float bf2f(unsigned short h) {
    union { unsigned int u; float f; } x; x.u = ((unsigned int)h) << 16;
    return x.f;
}

// ---------------- pre-pass: pack segmat+mask -> [b][i][j] {bf16 s0,s1,mk,0} ----
__global__ __launch_bounds__(256)
void pack_seg_kernel(const float* __restrict__ segmat,
                     const float* __restrict__ mask,
                     u16x4* __restrict__ segP)
{
    const int gid = blockIdx.x * 256 + threadIdx.x;   // over BSZ*QLEN*KLEN/8
    const int j8  = gid & (KLEN / 8 - 1);
    const int i   = (gid >> 7) & (QLEN - 1);
    const int b   = gid >> 17;
    const float* sp = segmat + ((size_t)(i * KLEN + j8 * 8) * BSZ + b) * 2;
    const float* mp = mask + (size_t)i * KLEN + j8 * 8;
    u16x4* op = segP + (size_t)(b * QLEN + i) * KLEN + j8 * 8;
#pragma unroll
    for (int e = 0; e < 8; ++e) {
        const f32x2 sm = *(const f32x2*)(sp + e * (BSZ * 2));
        u16x4 pk;
        pk[0] = f2bf(sm[0]); pk[1] = f2bf(sm[1]); pk[2] = f2bf(mp[e]); pk[3] = 0;
        op[e] = pk;
    }
}

// ---------------- merge: combine 2 j-half partials ----------------------------
__global__ __launch_bounds__(256)
void merge_kernel(const float* __restrict__ opart,
                  const float* __restrict__ ml,
                  float* __restrict__ out)
{
    const int gid = blockIdx.x * 256 + threadIdx.x;   // over 32768*64
    const int d   = gid & 63;
    const int rr  = gid >> 6;                          // (b*NHEAD+n)*QLEN + i
    const int i   = rr & (QLEN - 1);
    const int n   = (rr >> 10) & (NHEAD - 1);
    const int b   = rr >> 14;
    const int r0  = rr;
    const int r1  = (BSZ * NHEAD * QLEN) + rr;
    const float m0 = ml[r0 * 2], l0 = ml[r0 * 2 + 1];
    const float m1 = ml[r1 * 2], l1 = ml[r1 * 2 + 1];
    const float M  = fmaxf(m0, m1);
    const float w0 = __builtin_amdgcn_exp2f(m0 - M);
    const float w1 = __builtin_amdgcn_exp2f(m1 - M);
    const float inv = 1.f / (l0 * w0 + l1 * w1);
    const float o = (opart[(size_t)r0 * 64 + d] * w0 + opart[(size_t)r1 * 64 + d] * w1) * inv;
    out[(size_t)i * RS + b * NHEAD * DHEAD + n * DHEAD + d] = o;
}

// ---------------- main ---------------------------------------------------------
__global__ __launch_bounds__(256, 4)
void relattn_kernel(const float* __restrict__ q,
                    const float* __restrict__ kh,
                    const float* __restrict__ v,
                    const float* __restrict__ kr,
                    const float* __restrict__ segemb,
                    const float* __restrict__ segmat,
                    const float* __restrict__ rwb,
                    const float* __restrict__ rrb,
                    const float* __restrict__ rsb,
                    const float* __restrict__ mask,
                    const u16x4* __restrict__ segP,
                    float* __restrict__ opart,
                    float* __restrict__ mlpart,
                    float* __restrict__ out,
                    int packed, int jsplit, int njt)
{
    __shared__ unsigned short KhL[BLK_J][72];
    __shared__ unsigned short KrL[BLK_J][72];
    __shared__ unsigned short VtL[DHEAD][72];   // [d][j], granule swizzle (g+2(d&7))&7
    __shared__ unsigned short PlL[4][16][72];   // per-wave P tile
    __shared__ float ef0s[BLK_I][2];

    const int i0 = blockIdx.x * BLK_I;
    const int jh = blockIdx.y;
    const int b  = blockIdx.z & 1;
    const int n  = blockIdx.z >> 1;
    const int jbase = jh * (njt * BLK_J);

    const int tid  = threadIdx.x;
    const int wave = tid >> 6;
    const int lane = tid & 63;
    const int q4   = lane >> 4;
    const int c    = lane & 15;
    const int boff = b * NHEAD * DHEAD + n * DHEAD;

    // ---- prologue: ef0[i][s] = sum_d (q + r_s_bias) * seg_embed[s] ----
    if (tid < 2 * BLK_I) {
        const int il = tid >> 1;
        const int s  = tid & 1;
        const float* qp2 = q + (size_t)(i0 + il) * RS + boff;
        const float* se  = segemb + (s * NHEAD + n) * DHEAD;
        const float* rs  = rsb + n * DHEAD;
        float a = 0.f;
#pragma unroll
        for (int dd = 0; dd < DHEAD; dd += 4) {
            const f32x4 qv = *(const f32x4*)(qp2 + dd);
            const f32x4 sv = *(const f32x4*)(se + dd);
            const f32x4 rv = *(const f32x4*)(rs + dd);
#pragma unroll
            for (int e = 0; e < 4; ++e) a += (qv[e] + rv[e]) * sv[e];
        }
        ef0s[il][s] = a;
    }

    // ---- Q fragments straight from global ----
    s16x8 qwf[2], qrf[2];
    {
        const float* qp = q + (size_t)(i0 + wave * 16 + c) * RS + boff;
#pragma unroll
        for (int kk = 0; kk < 2; ++kk) {
            const int off = kk * 32 + q4 * 8;
            const f32x4 q0 = *(const f32x4*)(qp + off);
            const f32x4 q1 = *(const f32x4*)(qp + off + 4);
            const f32x4 w0 = *(const f32x4*)(rwb + n * DHEAD + off);
            const f32x4 w1 = *(const f32x4*)(rwb + n * DHEAD + off + 4);
            const f32x4 r0 = *(const f32x4*)(rrb + n * DHEAD + off);
            const f32x4 r1 = *(const f32x4*)(rrb + n * DHEAD + off + 4);
            s16x8 tw, tr;
#pragma unroll
            for (int e = 0; e < 4; ++e) {
                tw[e]     = (short)f2bf(q0[e] + w0[e]);
                tw[4 + e] = (short)f2bf(q1[e] + w1[e]);
                tr[e]     = (short)f2bf(q0[e] + r0[e]);
                tr[4 + e] = (short)f2bf(q1[e] + r1[e]);
            }
            qwf[kk] = tw; qrf[kk] = tr;
        }
    }
    __syncthreads();   // ef0s visible

    float e0[4], e1[4];
    int ig[4];
#pragma unroll
    for (int r = 0; r < 4; ++r) {
        const int iloc = wave * 16 + q4 * 4 + r;
        ig[r] = i0 + iloc;
        e0[r] = ef0s[iloc][0];
        e1[r] = ef0s[iloc][1];
    }

    float m[4], lsum[4];
    f32x4 acc[4];
#pragma unroll
    for (int r = 0; r < 4; ++r) { m[r] = -INFINITY; lsum[r] = 0.f; }
#pragma unroll
    for (int dt = 0; dt < 4; ++dt) acc[dt] = (f32x4)0.f;

    const int sr   = tid >> 2;         // staging row
    const int sc16 = (tid & 3) * 16;   // staging col base

    for (int jt = 0; jt < njt; ++jt) {
        const int j0 = jbase + jt * BLK_J;

        // ---- issue K/Kr/V loads (latency overlaps B0 barrier wait) ----
        f32x4 ka[4], ra[4];
        {
            const float* khp = kh + (size_t)(j0 + sr) * RS + boff + sc16;
            const float* krp = kr + (size_t)(j0 + sr + 1) * RS + boff + sc16; // shift +1
#pragma unroll
            for (int e = 0; e < 4; ++e) {
                ka[e] = *(const f32x4*)(khp + e * 4);
                ra[e] = *(const f32x4*)(krp + e * 4);
            }
        }
        float vv[16];
        {
            const float* vp = v + (size_t)(j0 + wave * 16) * RS + boff + lane;
#pragma unroll
            for (int jj = 0; jj < 16; ++jj) vv[jj] = vp[(size_t)jj * RS];
        }

        __syncthreads();   // B0: all waves done reading previous tile

        // ---- convert + write LDS ----
        {
            s16x8 h0, h1, r0, r1;
#pragma unroll
            for (int e = 0; e < 4; ++e) {
                h0[e] = (short)f2bf(ka[0][e]); h0[4 + e] = (short)f2bf(ka[1][e]);
                h1[e] = (short)f2bf(ka[2][e]); h1[4 + e] = (short)f2bf(ka[3][e]);
                r0[e] = (short)f2bf(ra[0][e]); r0[4 + e] = (short)f2bf(ra[1][e]);
                r1[e] = (short)f2bf(ra[2][e]); r1[4 + e] = (short)f2bf(ra[3][e]);
            }
            *(s16x8*)&KhL[sr][sc16]     = h0;
            *(s16x8*)&KhL[sr][sc16 + 8] = h1;
            *(s16x8*)&KrL[sr][sc16]     = r0;
            *(s16x8*)&KrL[sr][sc16 + 8] = r1;
        }
#pragma unroll
        for (int gg = 0; gg < 2; ++gg) {
            s16x8 vb;
#pragma unroll
            for (int e = 0; e < 8; ++e) vb[e] = (short)f2bf(vv[gg * 8 + e]);
            const int pg = ((wave * 2 + gg) + 2 * (lane & 7)) & 7;  // bijective swizzle
            *(s16x8*)&VtL[lane][pg * 8] = vb;
        }
        __syncthreads();   // B1: tile visible

        // ---- seg/mask bias gathers (issued now, consumed after QK) ----
        float bias[4][4];
        if (packed) {
            const u16x4* spB = segP + (size_t)(b * QLEN) * KLEN;
#pragma unroll
            for (int r = 0; r < 4; ++r) {
#pragma unroll
                for (int js = 0; js < 4; ++js) {
                    const u16x4 pk = spB[(size_t)ig[r] * KLEN + (j0 + js * 16 + c)];
                    bias[r][js] = (bf2f(pk[0]) * e0[r] + bf2f(pk[1]) * e1[r]) * SC2f
                                  - MBIGf * bf2f(pk[2]);
                }
            }
        } else {
#pragma unroll
            for (int r = 0; r < 4; ++r) {
#pragma unroll
                for (int js = 0; js < 4; ++js) {
                    const size_t sij = (size_t)ig[r] * KLEN + (j0 + js * 16 + c);
                    const f32x2 sm = *(const f32x2*)(segmat + (sij * 2 + b) * 2);
                    bias[r][js] = (sm[0] * e0[r] + sm[1] * e1[r]) * SC2f
                                  - MBIGf * mask[sij];
                }
            }
        }

        // ---- S = Qw*Kh^T + Qr*Kr^T ----
        f32x4 sj[4];
#pragma unroll
        for (int js = 0; js < 4; ++js) sj[js] = (f32x4)0.f;
        __builtin_amdgcn_s_setprio(1);
#pragma unroll
        for (int kk = 0; kk < 2; ++kk) {
#pragma unroll
            for (int js = 0; js < 4; ++js) {
                const s16x8 khf = *(const s16x8*)&KhL[js * 16 + c][kk * 32 + q4 * 8];
                const s16x8 krf = *(const s16x8*)&KrL[js * 16 + c][kk * 32 + q4 * 8];
                sj[js] = __builtin_amdgcn_mfma_f32_16x16x32_bf16(qwf[kk], khf, sj[js], 0, 0, 0);
                sj[js] = __builtin_amdgcn_mfma_f32_16x16x32_bf16(qrf[kk], krf, sj[js], 0, 0, 0);
            }
        }
        __builtin_amdgcn_s_setprio(0);

        // ---- bias + online softmax (log2 domain) ----
        float mt[4];
#pragma unroll
        for (int r = 0; r < 4; ++r) {
#pragma unroll
            for (int js = 0; js < 4; ++js)
                sj[js][r] = sj[js][r] * SC2f + bias[r][js];
            mt[r] = fmaxf(fmaxf(sj[0][r], sj[1][r]), fmaxf(sj[2][r], sj[3][r]));
        }
#pragma unroll
        for (int xm = 1; xm <= 8; xm <<= 1) {
#pragma unroll
            for (int r = 0; r < 4; ++r)
                mt[r] = fmaxf(mt[r], __shfl_xor(mt[r], xm, 64));
        }
#pragma unroll
        for (int r = 0; r < 4; ++r) {
            const float mn  = fmaxf(m[r], mt[r]);
            const float scl = __builtin_amdgcn_exp2f(m[r] - mn);
            m[r] = mn;
#pragma unroll
            for (int dt = 0; dt < 4; ++dt) acc[dt][r] *= scl;
            float ps = 0.f;
#pragma unroll
            for (int js = 0; js < 4; ++js) {
                const float p = __builtin_amdgcn_exp2f(sj[js][r] - mn);
                ps += p;
                PlL[wave][q4 * 4 + r][js * 16 + c] = f2bf(p);
            }
            lsum[r] = lsum[r] * scl + ps;   // per-lane partial
        }

        // ---- PV ----
        __builtin_amdgcn_s_setprio(1);
#pragma unroll
        for (int kk = 0; kk < 2; ++kk) {
            const s16x8 pf = *(const s16x8*)&PlL[wave][c][kk * 32 + q4 * 8];
#pragma unroll
            for (int dt = 0; dt < 4; ++dt) {
                const s16x8 vf = *(const s16x8*)&VtL[dt * 16 + c]
                                   [((kk * 4 + q4 + 2 * (c & 7)) & 7) * 8];
                acc[dt] = __builtin_amdgcn_mfma_f32_16x16x32_bf16(pf, vf, acc[dt], 0, 0, 0);
            }
        }
        __builtin_amdgcn_s_setprio(0);
    }

    // ---- epilogue: reduce lsum over 16 c-lanes ----
#pragma unroll
    for (int xm = 1; xm <= 8; xm <<= 1) {
#pragma unroll
        for (int r = 0; r < 4; ++r) lsum[r] += __shfl_xor(lsum[r], xm, 64);
    }
    if (jsplit) {
        const int rowbase = ((jh * BSZ + b) * NHEAD + n) * QLEN;
#pragma unroll
        for (int r = 0; r < 4; ++r) {
            float* op = opart + (size_t)(rowbase + ig[r]) * 64;
#pragma unroll
            for (int dt = 0; dt < 4; ++dt)
                op[dt * 16 + c] = acc[dt][r];
            if (c == 0) {
                mlpart[(size_t)(rowbase + ig[r]) * 2]     = m[r];
                mlpart[(size_t)(rowbase + ig[r]) * 2 + 1] = lsum[r];
            }
        }
    } else {
#pragma unroll
        for (int r = 0; r < 4; ++r) {
            const float inv = 1.f / lsum[r];
            float* op = out + (size_t)ig[r] * RS + boff;
#pragma unroll
            for (int dt = 0; dt < 4; ++dt)
                op[dt * 16 + c] = acc[dt][r] * inv;
        }
    }
}

extern "C" void kernel_launch(void* const* d_in, const int* in_sizes, int n_in,
                              void* d_out, int out_size, void* d_ws, size_t ws_size,
                              hipStream_t stream) {
    const float* q   = (const float*)d_in[0];
    const float* kh  = (const float*)d_in[1];
    const float* v   = (const float*)d_in[2];
    const float* kr  = (const float*)d_in[3];
    const float* se  = (const float*)d_in[4];
    const float* sm  = (const float*)d_in[5];
    const float* rwb = (const float*)d_in[6];
    const float* rrb = (const float*)d_in[7];
    const float* rsb = (const float*)d_in[8];
    const float* msk = (const float*)d_in[9];
    float* out = (float*)d_out;

    char* wsb = (char*)d_ws;
    u16x4* segP   = (u16x4*)wsb;
    float* opart  = (float*)(wsb + SEGP_BYTES);
    float* mlpart = (float*)(wsb + SEGP_BYTES + OPART_BYTES);

    const int packed = (ws_size >= SEGP_BYTES) ? 1 : 0;
    const int jsplit = (ws_size >= (size_t)SEGP_BYTES + OPART_BYTES + ML_BYTES) ? 1 : 0;
    const int njt    = jsplit ? (KLEN / BLK_J / 2) : (KLEN / BLK_J);

    if (packed)
        pack_seg_kernel<<<BSZ * QLEN * KLEN / 8 / 256, 256, 0, stream>>>(sm, msk, segP);

    dim3 grid(QLEN / BLK_I, jsplit ? 2 : 1, BSZ * NHEAD);
    relattn_kernel<<<grid, 256, 0, stream>>>(q, kh, v, kr, se, sm, rwb, rrb, rsb, msk,
                                             segP, opart, mlpart, out,
                                             packed, jsplit, njt);
    if (jsplit)
        merge_kernel<<<BSZ * NHEAD * QLEN * DHEAD / 256, 256, 0, stream>>>(opart, mlpart, out);
}

// Round 7
// 76.424 us; speedup vs baseline: 1.4614x; 1.4614x over previous
//
#include <hip/hip_runtime.h>

#define QLEN 1024
#define KLEN 1024
#define BSZ 2
#define NHEAD 16
#define DHEAD 64
#define RS 2048            /* BSZ*NHEAD*DHEAD floats per seq row */
#define BLK_I 64
#define BLK_J 64
#define NJT (KLEN / BLK_J)
#define NBN (BSZ * NHEAD)

#define SC2f  0.18033688011112440f   /* 0.125 * log2(e) */
#define MBIGf 1.4426950408889634e30f /* 1e30 * log2(e)  */

#define SEGP_BYTES  16777216u                 /* BSZ*QLEN*KLEN*8  */
#define KT_BYTES    ((size_t)NBN * NJT * 8192) /* 4 MiB per tensor */

typedef __attribute__((ext_vector_type(8))) short s16x8;
typedef __attribute__((ext_vector_type(8))) unsigned short u16x8;
typedef __attribute__((ext_vector_type(4))) unsigned short u16x4;
typedef __attribute__((ext_vector_type(4))) float f32x4;
typedef __attribute__((ext_vector_type(2))) float f32x2;

__device__ __forceinline__ unsigned short f2bf(float f) {
    union { float f; unsigned int u; } x; x.f = f;
    unsigned int r = x.u + 0x7fffu + ((x.u >> 16) & 1u);
    return (unsigned short)(r >> 16);
}
__device__ __forceinline__ float bf2f(unsigned short h) {
    union { unsigned int u; float f; } x; x.u = ((unsigned int)h) << 16;
    return x.f;
}

typedef const __attribute__((address_space(1))) unsigned int* gas_t;
typedef __attribute__((address_space(3))) unsigned int* las_t;
__device__ __forceinline__ void gl_lds16(const void* g, void* l) {
    __builtin_amdgcn_global_load_lds((gas_t)g, (las_t)l, 16, 0, 0);
}

// ---- pre-pass 1: pack segmat+mask -> [b][i][j] {bf16 s0, s1, mk*MBIG, 0} ----
__global__ __launch_bounds__(256)
void pack_seg_kernel(const float* __restrict__ segmat,
                     const float* __restrict__ mask,
                     u16x4* __restrict__ segP)
{
    const int gid = blockIdx.x * 256 + threadIdx.x;   // BSZ*QLEN*KLEN/8 items
    const int j8  = gid & (KLEN / 8 - 1);
    const int i   = (gid >> 7) & (QLEN - 1);
    const int b   = gid >> 17;
    const float* sp = segmat + ((size_t)(i * KLEN + j8 * 8) * BSZ + b) * 2;
    const float* mp = mask + (size_t)i * KLEN + j8 * 8;
    u16x4* op = segP + (size_t)(b * QLEN + i) * KLEN + j8 * 8;
#pragma unroll
    for (int e = 0; e < 8; ++e) {
        const f32x2 sm = *(const f32x2*)(sp + e * (BSZ * 2));
        u16x4 pk;
        pk[0] = f2bf(sm[0]); pk[1] = f2bf(sm[1]);
        pk[2] = f2bf(mp[e] * MBIGf); pk[3] = 0;
        op[e] = pk;
    }
}

// ---- pre-pass 2: pack Kh, Kr(+1), V^T as flat 8KB bf16 tiles, swizzled ------
// tile layout byte p: row = p>>7, pc = (p>>4)&7; logical chunk = pc ^ (row&7);
// K tiles:  elem = kh[j0+row][chunk*8+e]      (row = j)
// Vt tiles: elem = v[j0 + chunk*8+e][row]     (row = d)  -- transpose via LDS
__global__ __launch_bounds__(256)
void pack_kv_kernel(const float* __restrict__ kh,
                    const float* __restrict__ kr,
                    const float* __restrict__ v,
                    unsigned short* __restrict__ Kp,
                    unsigned short* __restrict__ Krp,
                    unsigned short* __restrict__ Vtp)
{
    __shared__ float VT[64][65];
    const int blk = blockIdx.x;           // bn*NJT + jt
    const int bn  = blk >> 4;
    const int jt  = blk & (NJT - 1);
    const int b   = bn & 1;
    const int n   = bn >> 1;
    const int boff = b * NHEAD * DHEAD + n * DHEAD;
    const int j0  = jt * BLK_J;
    const int tid = threadIdx.x;

    {   // v tile -> LDS (coalesced)
        const int j  = tid >> 2;
        const int dq = (tid & 3) * 16;
        const float* vp = v + (size_t)(j0 + j) * RS + boff + dq;
#pragma unroll
        for (int e = 0; e < 16; ++e) VT[j][dq + e] = vp[e];
    }
    __syncthreads();

    const size_t tb = (size_t)blk * 4096;   // u16 units (8KB tiles)
#pragma unroll
    for (int h = 0; h < 2; ++h) {
        const int p   = tid + h * 256;      // chunk 0..511
        const int row = p >> 3;
        const int ch  = (p & 7) ^ (row & 7);
        u16x8 ok, orr, ov;
        const float* hp = kh + (size_t)(j0 + row) * RS + boff + ch * 8;
        const float* rp = kr + (size_t)(j0 + row + 1) * RS + boff + ch * 8; // shift +1
#pragma unroll
        for (int e = 0; e < 8; ++e) {
            ok[e]  = f2bf(hp[e]);
            orr[e] = f2bf(rp[e]);
            ov[e]  = f2bf(VT[ch * 8 + e][row]);
        }
        *(u16x8*)&Kp [tb + (size_t)p * 8] = ok;
        *(u16x8*)&Krp[tb + (size_t)p * 8] = orr;
        *(u16x8*)&Vtp[tb + (size_t)p * 8] = ov;
    }
}

// ---- main -------------------------------------------------------------------
__global__ __launch_bounds__(256, 2)
void relattn_kernel(const float* __restrict__ q,
                    const float* __restrict__ segemb,
                    const float* __restrict__ rwb,
                    const float* __restrict__ rrb,
                    const float* __restrict__ rsb,
                    const u16x4* __restrict__ segP,
                    const unsigned short* __restrict__ Kp,
                    const unsigned short* __restrict__ Krp,
                    const unsigned short* __restrict__ Vtp,
                    float* __restrict__ out)
{
    __shared__ unsigned short KhL[2][BLK_J][64];
    __shared__ unsigned short KrL[2][BLK_J][64];
    __shared__ unsigned short VtL[2][DHEAD][64];
    __shared__ unsigned short PlL[4][32][40];   // per-wave 32x32 P
    __shared__ float ef0s[BLK_I][2];

    const int i0 = blockIdx.x * BLK_I;
    const int bn = blockIdx.y;
    const int b  = bn & 1;
    const int n  = bn >> 1;
    const int boff = b * NHEAD * DHEAD + n * DHEAD;

    const int tid  = threadIdx.x;
    const int wave = tid >> 6;
    const int lane = tid & 63;
    const int q4   = lane >> 4;
    const int c    = lane & 15;
    const int ih   = wave >> 1;   // i-half: rows ih*32..+32
    const int jh   = wave & 1;    // j-half: cols jh*32..+32

    // ---- ef0[i][s] = sum_d (q + r_s_bias) * seg_embed[s] ----
    if (tid < 2 * BLK_I) {
        const int il = tid >> 1;
        const int s  = tid & 1;
        const float* qp2 = q + (size_t)(i0 + il) * RS + boff;
        const float* se  = segemb + (s * NHEAD + n) * DHEAD;
        const float* rs  = rsb + n * DHEAD;
        float a = 0.f;
#pragma unroll
        for (int dd = 0; dd < DHEAD; dd += 4) {
            const f32x4 qv = *(const f32x4*)(qp2 + dd);
            const f32x4 sv = *(const f32x4*)(se + dd);
            const f32x4 rv = *(const f32x4*)(rs + dd);
#pragma unroll
            for (int e = 0; e < 4; ++e) a += (qv[e] + rv[e]) * sv[e];
        }
        ef0s[il][s] = a;
    }

    // ---- Q fragments from global (rows i0 + ih*32 + isub*16 + c) ----
    s16x8 qwf[2][2], qrf[2][2];
#pragma unroll
    for (int isub = 0; isub < 2; ++isub) {
        const float* qp = q + (size_t)(i0 + ih * 32 + isub * 16 + c) * RS + boff;
#pragma unroll
        for (int kk = 0; kk < 2; ++kk) {
            const int off = kk * 32 + q4 * 8;
            const f32x4 q0 = *(const f32x4*)(qp + off);
            const f32x4 q1 = *(const f32x4*)(qp + off + 4);
            const f32x4 w0 = *(const f32x4*)(rwb + n * DHEAD + off);
            const f32x4 w1 = *(const f32x4*)(rwb + n * DHEAD + off + 4);
            const f32x4 r0 = *(const f32x4*)(rrb + n * DHEAD + off);
            const f32x4 r1 = *(const f32x4*)(rrb + n * DHEAD + off + 4);
            s16x8 tw, tr;
#pragma unroll
            for (int e = 0; e < 4; ++e) {
                tw[e]     = (short)f2bf(q0[e] + w0[e]);
                tw[4 + e] = (short)f2bf(q1[e] + w1[e]);
                tr[e]     = (short)f2bf(q0[e] + r0[e]);
                tr[4 + e] = (short)f2bf(q1[e] + r1[e]);
            }
            qwf[isub][kk] = tw; qrf[isub][kk] = tr;
        }
    }

    // ---- async DMA staging (no VGPR round-trip; cannot be sunk) ----
    const char* KpB  = (const char*)Kp;
    const char* KrpB = (const char*)Krp;
    const char* VtpB = (const char*)Vtp;
    auto stage = [&](int jt, int buf) {
        const size_t toff = ((size_t)(bn * NJT + jt)) << 13;
        const int go = wave * 1024 + lane * 16;
        const int lo = wave * 1024;
#pragma unroll
        for (int h = 0; h < 2; ++h) {
            gl_lds16(KpB  + toff + go + h * 4096, (char*)&KhL[buf][0][0] + lo + h * 4096);
            gl_lds16(KrpB + toff + go + h * 4096, (char*)&KrL[buf][0][0] + lo + h * 4096);
            gl_lds16(VtpB + toff + go + h * 4096, (char*)&VtL[buf][0][0] + lo + h * 4096);
        }
    };

    stage(0, 0);
    __syncthreads();   // tile 0 + ef0s ready

    float e0s[2][4], e1s[2][4];
    int igr[2][4];
#pragma unroll
    for (int isub = 0; isub < 2; ++isub)
#pragma unroll
        for (int r = 0; r < 4; ++r) {
            const int iloc = ih * 32 + isub * 16 + q4 * 4 + r;
            igr[isub][r] = i0 + iloc;
            e0s[isub][r] = ef0s[iloc][0] * SC2f;   // fold SC2 into ef
            e1s[isub][r] = ef0s[iloc][1] * SC2f;
        }

    float m[2][4], lsum[2][4];
    f32x4 acc[2][4];
#pragma unroll
    for (int isub = 0; isub < 2; ++isub)
#pragma unroll
        for (int r = 0; r < 4; ++r) { m[isub][r] = -INFINITY; lsum[isub][r] = 0.f; }
#pragma unroll
    for (int isub = 0; isub < 2; ++isub)
#pragma unroll
        for (int dt = 0; dt < 4; ++dt) acc[isub][dt] = (f32x4)0.f;

    const u16x4* spB = segP + (size_t)b * QLEN * KLEN;
    int cur = 0;
    for (int jt = 0; jt < NJT; ++jt) {
        if (jt + 1 < NJT) stage(jt + 1, cur ^ 1);   // DMA overlaps compute below

        // ---- seg/mask bias gathers for this tile (consumed post-QK) ----
        const int jb = jt * BLK_J + jh * 32;
        u16x4 pk[2][4][2];
#pragma unroll
        for (int isub = 0; isub < 2; ++isub)
#pragma unroll
            for (int r = 0; r < 4; ++r)
#pragma unroll
                for (int js = 0; js < 2; ++js)
                    pk[isub][r][js] = spB[(size_t)igr[isub][r] * KLEN + jb + js * 16 + c];

        // ---- S quadrant = Qw*Kh^T + Qr*Kr^T (16 MFMA) ----
        f32x4 sj[2][2];
#pragma unroll
        for (int isub = 0; isub < 2; ++isub) { sj[isub][0] = (f32x4)0.f; sj[isub][1] = (f32x4)0.f; }
        __builtin_amdgcn_s_setprio(1);
#pragma unroll
        for (int kk = 0; kk < 2; ++kk)
#pragma unroll
            for (int js = 0; js < 2; ++js) {
                const int row = jh * 32 + js * 16 + c;
                const int pcK = ((kk * 4 + q4) ^ (c & 7)) * 8;
                const s16x8 khf = *(const s16x8*)&KhL[cur][row][pcK];
                const s16x8 krf = *(const s16x8*)&KrL[cur][row][pcK];
#pragma unroll
                for (int isub = 0; isub < 2; ++isub) {
                    sj[isub][js] = __builtin_amdgcn_mfma_f32_16x16x32_bf16(qwf[isub][kk], khf, sj[isub][js], 0, 0, 0);
                    sj[isub][js] = __builtin_amdgcn_mfma_f32_16x16x32_bf16(qrf[isub][kk], krf, sj[isub][js], 0, 0, 0);
                }
            }
        __builtin_amdgcn_s_setprio(0);

        // ---- bias + online softmax over this wave's 32 j ----
        float mt[2][4];
#pragma unroll
        for (int isub = 0; isub < 2; ++isub)
#pragma unroll
            for (int r = 0; r < 4; ++r) {
#pragma unroll
                for (int js = 0; js < 2; ++js) {
                    const u16x4 p = pk[isub][r][js];
                    const float bias = bf2f(p[0]) * e0s[isub][r] + bf2f(p[1]) * e1s[isub][r]
                                       - bf2f(p[2]);
                    sj[isub][js][r] = sj[isub][js][r] * SC2f + bias;
                }
                mt[isub][r] = fmaxf(sj[isub][0][r], sj[isub][1][r]);
            }
#pragma unroll
        for (int xm = 1; xm <= 8; xm <<= 1)
#pragma unroll
            for (int isub = 0; isub < 2; ++isub)
#pragma unroll
                for (int r = 0; r < 4; ++r)
                    mt[isub][r] = fmaxf(mt[isub][r], __shfl_xor(mt[isub][r], xm, 64));
#pragma unroll
        for (int isub = 0; isub < 2; ++isub)
#pragma unroll
            for (int r = 0; r < 4; ++r) {
                const float mn  = fmaxf(m[isub][r], mt[isub][r]);
                const float scl = __builtin_amdgcn_exp2f(m[isub][r] - mn);
                m[isub][r] = mn;
#pragma unroll
                for (int dt = 0; dt < 4; ++dt) acc[isub][dt][r] *= scl;
                float ps = 0.f;
#pragma unroll
                for (int js = 0; js < 2; ++js) {
                    const float p = __builtin_amdgcn_exp2f(sj[isub][js][r] - mn);
                    ps += p;
                    PlL[wave][isub * 16 + q4 * 4 + r][js * 16 + c] = f2bf(p);
                }
                lsum[isub][r] = lsum[isub][r] * scl + ps;   // per-lane partial
            }

        // ---- PV: acc += P(32x32) * V(32x64), K=32 in one MFMA step ----
        __builtin_amdgcn_s_setprio(1);
        {
            s16x8 vf[4];
            const int pcV = ((jh * 4 + q4) ^ (c & 7)) * 8;
#pragma unroll
            for (int dt = 0; dt < 4; ++dt)
                vf[dt] = *(const s16x8*)&VtL[cur][dt * 16 + c][pcV];
#pragma unroll
            for (int isub = 0; isub < 2; ++isub) {
                const s16x8 pf = *(const s16x8*)&PlL[wave][isub * 16 + c][q4 * 8];
#pragma unroll
                for (int dt = 0; dt < 4; ++dt)
                    acc[isub][dt] = __builtin_amdgcn_mfma_f32_16x16x32_bf16(pf, vf[dt], acc[isub][dt], 0, 0, 0);
            }
        }
        __builtin_amdgcn_s_setprio(0);

        __syncthreads();   // drains DMA (vmcnt 0) + all waves done with buf[cur]
        cur ^= 1;
    }

    // ---- epilogue: reduce lsum over c-lanes; merge j-halves via LDS ----
#pragma unroll
    for (int xm = 1; xm <= 8; xm <<= 1)
#pragma unroll
        for (int isub = 0; isub < 2; ++isub)
#pragma unroll
            for (int r = 0; r < 4; ++r)
                lsum[isub][r] += __shfl_xor(lsum[isub][r], xm, 64);

    float* scrO  = (float*)&KhL[0][0][0];   // 16 KB: [64][64] partial O (jh=1)
    float* scrML = (float*)&KrL[0][0][0];   // [64][2] m,l (jh=1)
    if (jh == 1) {
#pragma unroll
        for (int isub = 0; isub < 2; ++isub)
#pragma unroll
            for (int r = 0; r < 4; ++r) {
                const int rowL = ih * 32 + isub * 16 + q4 * 4 + r;
#pragma unroll
                for (int dt = 0; dt < 4; ++dt)
                    scrO[rowL * 64 + dt * 16 + c] = acc[isub][dt][r];
                if (c == 0) {
                    scrML[rowL * 2]     = m[isub][r];
                    scrML[rowL * 2 + 1] = lsum[isub][r];
                }
            }
    }
    __syncthreads();
    if (jh == 0) {
#pragma unroll
        for (int isub = 0; isub < 2; ++isub)
#pragma unroll
            for (int r = 0; r < 4; ++r) {
                const int rowL = ih * 32 + isub * 16 + q4 * 4 + r;
                const float m1 = scrML[rowL * 2];
                const float l1 = scrML[rowL * 2 + 1];
                const float M  = fmaxf(m[isub][r], m1);
                const float w0 = __builtin_amdgcn_exp2f(m[isub][r] - M);
                const float w1 = __builtin_amdgcn_exp2f(m1 - M);
                const float inv = 1.f / (lsum[isub][r] * w0 + l1 * w1);
                float* op = out + (size_t)(i0 + rowL) * RS + boff;
#pragma unroll
                for (int dt = 0; dt < 4; ++dt)
                    op[dt * 16 + c] = (acc[isub][dt][r] * w0 + scrO[rowL * 64 + dt * 16 + c] * w1) * inv;
            }
    }
}

extern "C" void kernel_launch(void* const* d_in, const int* in_sizes, int n_in,
                              void* d_out, int out_size, void* d_ws, size_t ws_size,
                              hipStream_t stream) {
    const float* q   = (const float*)d_in[0];
    const float* kh  = (const float*)d_in[1];
    const float* v   = (const float*)d_in[2];
    const float* kr  = (const float*)d_in[3];
    const float* se  = (const float*)d_in[4];
    const float* sm  = (const float*)d_in[5];
    const float* rwb = (const float*)d_in[6];
    const float* rrb = (const float*)d_in[7];
    const float* rsb = (const float*)d_in[8];
    const float* msk = (const float*)d_in[9];
    float* out = (float*)d_out;

    char* wsb = (char*)d_ws;   // need 16.8 + 3*4.2 = 29.4 MB (r6 proved >=34 MB)
    u16x4* segP = (u16x4*)wsb;
    unsigned short* Kp  = (unsigned short*)(wsb + SEGP_BYTES);
    unsigned short* Krp = (unsigned short*)(wsb + SEGP_BYTES + KT_BYTES);
    unsigned short* Vtp = (unsigned short*)(wsb + SEGP_BYTES + 2 * KT_BYTES);

    pack_seg_kernel<<<BSZ * QLEN * KLEN / 8 / 256, 256, 0, stream>>>(sm, msk, segP);
    pack_kv_kernel<<<NBN * NJT, 256, 0, stream>>>(kh, kr, v, Kp, Krp, Vtp);
    dim3 grid(QLEN / BLK_I, NBN);
    relattn_kernel<<<grid, 256, 0, stream>>>(q, se, rwb, rrb, rsb, segP, Kp, Krp, Vtp, out);
}